// Round 10
// baseline (318.751 us; speedup 1.0000x reference)
//
#include <hip/hip_runtime.h>
#include <hip/hip_bf16.h>

// SGConv (K=2) on MI355X.
// R4: MFMA matmul. R6: bucket build + counting sort -> CSR gather hops.
// R7: bf16 z-tables. R8: gather unroll x4 + fused hop2/log_softmax.
// R9: hops unroll x8 (more MLP on the latency-bound gather chain);
//     k_part loses the 32KB LDS stash (re-read dst from L2, 4KB LDS,
//     high occupancy) and ETILE doubles to 16384 (fewer bcur atomic
//     rounds, longer per-bucket write runs -> fewer partial sectors).

#define TPB 256
#define ETILE 16384                // edges per partition block

typedef __attribute__((ext_vector_type(8))) short short8v;   // bf16x8
typedef __attribute__((ext_vector_type(4))) float f32x4;

__device__ inline short f2bf(float f) {            // RNE f32->bf16
    unsigned u = __float_as_uint(f);
    unsigned r = (u + 0x7fffu + ((u >> 16) & 1u)) >> 16;
    return (short)r;
}
__device__ inline float bf2f(short s) {
    return __uint_as_float(((unsigned)(unsigned short)s) << 16);
}

// ---- W -> Wb (48x512 bf16) and (block 0) zero bcnt ---------------------
__global__ void k_wconv(const float* __restrict__ W, short* __restrict__ Wb,
                        int* __restrict__ bcnt, int nb) {
    if (blockIdx.x == 0)
        for (int i = threadIdx.x; i < nb; i += TPB) bcnt[i] = 0;
    int idx = blockIdx.x * TPB + threadIdx.x;    // 0..24575
    int c = idx >> 9, k = idx & 511;
    float v = (c < 40) ? W[c * 512 + k] : 0.f;
    Wb[idx] = f2bf(v);
}

// ---- per-bucket edge histogram (bucket = dst>>8) -----------------------
__global__ __launch_bounds__(TPB) void k_bhist(
    const int* __restrict__ dst, int* __restrict__ bcnt, int E, int nb) {
    __shared__ int h[512];
    int t = threadIdx.x;
    for (int i = t; i < nb; i += TPB) h[i] = 0;
    __syncthreads();
    int e0 = blockIdx.x * ETILE;
    int e1 = min(e0 + ETILE, E);
    for (int e = e0 + t; e < e1; e += TPB)
        atomicAdd(&h[dst[e] >> 8], 1);
    __syncthreads();
    for (int i = t; i < nb; i += TPB)
        if (h[i]) atomicAdd(&bcnt[i], h[i]);
}

// ---- 391-entry exclusive scan -> boff, bcur (single block) -------------
__global__ __launch_bounds__(512) void k_boff(
    const int* __restrict__ bcnt, int* __restrict__ boff,
    int* __restrict__ bcur, int nb) {
    __shared__ int s[512];
    int t = threadIdx.x;
    int own = (t < nb) ? bcnt[t] : 0;
    s[t] = own;
    __syncthreads();
    for (int off = 1; off < 512; off <<= 1) {
        int v = (t >= off) ? s[t - off] : 0;
        __syncthreads();
        s[t] += v;
        __syncthreads();
    }
    if (t < nb) {
        int ex = s[t] - own;
        boff[t] = ex;
        bcur[t] = ex;
        if (t == nb - 1) boff[nb] = s[t];
    }
}

// ---- block-aggregated bucket partition (no stash: dst read twice) ------
__global__ __launch_bounds__(TPB) void k_part(
    const int* __restrict__ src, const int* __restrict__ dst,
    int* __restrict__ bcur, int* __restrict__ pairs, int E, int nb) {
    __shared__ int hist[512], base[512];
    int t = threadIdx.x;
    for (int i = t; i < nb; i += TPB) hist[i] = 0;
    __syncthreads();
    int e0 = blockIdx.x * ETILE;
    int e1 = min(e0 + ETILE, E);
    for (int e = e0 + t; e < e1; e += TPB)
        atomicAdd(&hist[dst[e] >> 8], 1);
    __syncthreads();
    for (int i = t; i < nb; i += TPB) {
        base[i] = hist[i] ? atomicAdd(&bcur[i], hist[i]) : 0;
        hist[i] = 0;                         // reuse as local cursor
    }
    __syncthreads();
    for (int e = e0 + t; e < e1; e += TPB) { // dst re-read: L2-warm
        int d = dst[e];
        int b = d >> 8;
        int pos = base[b] + atomicAdd(&hist[b], 1);
        pairs[pos] = ((d & 255) << 20) | src[e];   // src < 2^20
    }
}

// ---- per-bucket counting sort: pairs -> dst-sorted csr + row_ptr + dinv
__global__ __launch_bounds__(TPB) void k_sort(
    const int* __restrict__ pairs, const int* __restrict__ boff,
    int* __restrict__ csr, int* __restrict__ row_ptr, float* __restrict__ dinv,
    int N, int nb) {
    __shared__ int hist[256], excl[256], lcur[256];
    int b = blockIdx.x, t = threadIdx.x;
    hist[t] = 0;
    __syncthreads();
    int beg = boff[b], end = boff[b + 1];
    for (int j = beg + t; j < end; j += TPB)
        atomicAdd(&hist[pairs[j] >> 20], 1);
    __syncthreads();
    int own = hist[t];
    excl[t] = own;
    __syncthreads();
    for (int off = 1; off < 256; off <<= 1) {
        int v = (t >= off) ? excl[t - off] : 0;
        __syncthreads();
        excl[t] += v;
        __syncthreads();
    }
    int node = (b << 8) + t;
    if (node < N) {
        row_ptr[node] = beg + excl[t] - own;   // global exclusive offset
        dinv[node] = rsqrtf((float)(own + 1)); // +1 self-loop
    }
    lcur[t] = 0;
    __syncthreads();
    for (int j = beg + t; j < end; j += TPB) {
        int u = pairs[j];
        int dl = u >> 20;
        int pos = beg + (excl[dl] - hist[dl]) + atomicAdd(&lcur[dl], 1);
        csr[pos] = u & 0xFFFFF;
    }
    if (b == nb - 1 && t == 0) row_ptr[N] = end;
}

// ---- z0 = bf16( dinv .* (x @ W^T) ) via MFMA bf16 ----------------------
__global__ __launch_bounds__(TPB) void k_matmul_mfma(
    const float* __restrict__ x, const short* __restrict__ Wb,
    const float* __restrict__ dinv, short* __restrict__ z, int N) {
    int wid  = threadIdx.x >> 6;
    int lane = threadIdx.x & 63;
    int rbase = blockIdx.x * 64 + wid * 16;
    if (rbase >= N) return;
    int arow   = rbase + (lane & 15);
    int aclamp = min(arow, N - 1);
    int koff   = (lane >> 4) * 8;
    const float* xrow = x + (size_t)aclamp * 512 + koff;
    const short* wb   = Wb + (lane & 15) * 512 + koff;

    f32x4 acc0 = {0.f,0.f,0.f,0.f}, acc1 = {0.f,0.f,0.f,0.f}, acc2 = {0.f,0.f,0.f,0.f};
    for (int ks = 0; ks < 16; ++ks) {
        int k0 = ks * 32;
        float4 f0 = *reinterpret_cast<const float4*>(xrow + k0);
        float4 f1 = *reinterpret_cast<const float4*>(xrow + k0 + 4);
        short8v a;
        a[0] = f2bf(f0.x); a[1] = f2bf(f0.y); a[2] = f2bf(f0.z); a[3] = f2bf(f0.w);
        a[4] = f2bf(f1.x); a[5] = f2bf(f1.y); a[6] = f2bf(f1.z); a[7] = f2bf(f1.w);
        short8v b0 = *reinterpret_cast<const short8v*>(wb + k0);
        short8v b1 = *reinterpret_cast<const short8v*>(wb + 16 * 512 + k0);
        short8v b2 = *reinterpret_cast<const short8v*>(wb + 32 * 512 + k0);
        acc0 = __builtin_amdgcn_mfma_f32_16x16x32_bf16(a, b0, acc0, 0, 0, 0);
        acc1 = __builtin_amdgcn_mfma_f32_16x16x32_bf16(a, b1, acc1, 0, 0, 0);
        acc2 = __builtin_amdgcn_mfma_f32_16x16x32_bf16(a, b2, acc2, 0, 0, 0);
    }
    int col = lane & 15;
    int rw  = rbase + (lane >> 4) * 4;
#pragma unroll
    for (int reg = 0; reg < 4; ++reg) {
        int r = rw + reg;
        if (r < N) {
            float di = dinv[r];
            z[(size_t)r * 40 + col]      = f2bf(di * acc0[reg]);
            z[(size_t)r * 40 + 16 + col] = f2bf(di * acc1[reg]);
            if (col < 8)
                z[(size_t)r * 40 + 32 + col] = f2bf(di * acc2[reg]);
        }
    }
}

// ---- shared gather body: acc[8] += sum_{s in csr[beg..end)} zin[s] -----
// unroll x8: 8 independent 16B loads in flight per lane.
__device__ inline void gather_acc(
    const short8v* __restrict__ Z, const int* __restrict__ csr,
    int beg, int end, int c8, float acc[8]) {
    int j = beg;
    for (; j + 8 <= end; j += 8) {
        int s0 = csr[j],   s1 = csr[j+1], s2 = csr[j+2], s3 = csr[j+3];
        int s4 = csr[j+4], s5 = csr[j+5], s6 = csr[j+6], s7 = csr[j+7];
        short8v v0 = Z[s0 * 5 + c8];
        short8v v1 = Z[s1 * 5 + c8];
        short8v v2 = Z[s2 * 5 + c8];
        short8v v3 = Z[s3 * 5 + c8];
        short8v v4 = Z[s4 * 5 + c8];
        short8v v5 = Z[s5 * 5 + c8];
        short8v v6 = Z[s6 * 5 + c8];
        short8v v7 = Z[s7 * 5 + c8];
#pragma unroll
        for (int k = 0; k < 8; ++k)
            acc[k] += ((bf2f(v0[k]) + bf2f(v1[k])) + (bf2f(v2[k]) + bf2f(v3[k])))
                    + ((bf2f(v4[k]) + bf2f(v5[k])) + (bf2f(v6[k]) + bf2f(v7[k])));
    }
    for (; j + 4 <= end; j += 4) {
        int s0 = csr[j], s1 = csr[j+1], s2 = csr[j+2], s3 = csr[j+3];
        short8v v0 = Z[s0 * 5 + c8];
        short8v v1 = Z[s1 * 5 + c8];
        short8v v2 = Z[s2 * 5 + c8];
        short8v v3 = Z[s3 * 5 + c8];
#pragma unroll
        for (int k = 0; k < 8; ++k)
            acc[k] += (bf2f(v0[k]) + bf2f(v1[k])) + (bf2f(v2[k]) + bf2f(v3[k]));
    }
    for (; j < end; ++j) {
        short8v v = Z[csr[j] * 5 + c8];
#pragma unroll
        for (int k = 0; k < 8; ++k) acc[k] += bf2f(v[k]);
    }
}

// ---- hop1: z1 = bf16( dinv^2 .* (A z0) ), 5 lanes/node -----------------
__global__ __launch_bounds__(TPB) void k_hop1(
    const int* __restrict__ csr, const int* __restrict__ row_ptr,
    const float* __restrict__ dinv, const short* __restrict__ zin,
    short* __restrict__ zout, int N) {
    int t = blockIdx.x * TPB + threadIdx.x;
    int node = t / 5;
    int c8 = t - node * 5;
    if (node >= N) return;
    const short8v* Z = reinterpret_cast<const short8v*>(zin);
    short8v sv = Z[node * 5 + c8];             // self-loop term
    float acc[8];
#pragma unroll
    for (int k = 0; k < 8; ++k) acc[k] = bf2f(sv[k]);
    gather_acc(Z, csr, row_ptr[node], row_ptr[node + 1], c8, acc);
    float dd = dinv[node];
    float sc = dd * dd;
    short8v o;
#pragma unroll
    for (int k = 0; k < 8; ++k) o[k] = f2bf(sc * acc[k]);
    reinterpret_cast<short8v*>(zout)[node * 5 + c8] = o;
}

// ---- hop2 fused with bias + log_softmax --------------------------------
// Wave handles 12 nodes in lanes 0..59 (groups of 5); lanes 60..63 idle.
__global__ __launch_bounds__(TPB) void k_hop2_lsm(
    const int* __restrict__ csr, const int* __restrict__ row_ptr,
    const float* __restrict__ dinv, const short* __restrict__ zin,
    const float* __restrict__ bias, float* __restrict__ out, int N) {
    int wid  = threadIdx.x >> 6;
    int lane = threadIdx.x & 63;
    int g    = lane / 5;
    int c8   = lane - g * 5;
    int node = (blockIdx.x * 4 + wid) * 12 + g;
    bool active = (g < 12) && (node < N);

    float v[8];
    float lm = -1e30f;
    if (active) {
        const short8v* Z = reinterpret_cast<const short8v*>(zin);
        short8v sv = Z[node * 5 + c8];
        float acc[8];
#pragma unroll
        for (int k = 0; k < 8; ++k) acc[k] = bf2f(sv[k]);
        gather_acc(Z, csr, row_ptr[node], row_ptr[node + 1], c8, acc);
        float dd = dinv[node];
#pragma unroll
        for (int k = 0; k < 8; ++k) {
            v[k] = dd * acc[k] + bias[c8 * 8 + k];
            lm = fmaxf(lm, v[k]);
        }
    }
    int base = g * 5;                     // group leader lane (uniform in group)
    float gm = lm;
#pragma unroll
    for (int k = 0; k < 5; ++k) gm = fmaxf(gm, __shfl(lm, base + k, 64));
    float ls = 0.f;
    if (active) {
#pragma unroll
        for (int k = 0; k < 8; ++k) ls += __expf(v[k] - gm);
    }
    float tot = 0.f;
#pragma unroll
    for (int k = 0; k < 5; ++k) tot += __shfl(ls, base + k, 64);
    if (active) {
        float lse = gm + __logf(tot);
        float* op = out + (size_t)node * 40 + c8 * 8;
        *reinterpret_cast<float4*>(op)     = make_float4(v[0]-lse, v[1]-lse, v[2]-lse, v[3]-lse);
        *reinterpret_cast<float4*>(op + 4) = make_float4(v[4]-lse, v[5]-lse, v[6]-lse, v[7]-lse);
    }
}

extern "C" void kernel_launch(void* const* d_in, const int* in_sizes, int n_in,
                              void* d_out, int out_size, void* d_ws, size_t ws_size,
                              hipStream_t stream) {
    const float* x  = (const float*)d_in[0];
    const int*   ei = (const int*)d_in[1];
    const float* W  = (const float*)d_in[2];
    const float* b  = (const float*)d_in[3];
    float* out = (float*)d_out;

    const int N = in_sizes[0] / 512;     // 100000
    const int E = in_sizes[1] / 2;       // 3200000
    const int* src = ei;                 // edge_index[0]
    const int* dst = ei + E;             // edge_index[1]
    const int nb = (N + 255) >> 8;       // 391 buckets

    // workspace: z0b [N*40 bf16] | z1b [N*40 bf16] | csr [E] | pairs [E]
    //   | bcnt [nb] | boff [nb+1] | bcur [nb] | row_ptr [N+1] | dinv [N]
    //   | Wb [48*512 bf16]     (~42 MB total)
    short* z0b     = (short*)d_ws;
    short* z1b     = z0b + (size_t)N * 40;
    int*   csr     = (int*)(z1b + (size_t)N * 40);
    int*   pairs   = csr + E;
    int*   bcnt    = pairs + E;
    int*   boff    = bcnt + nb;
    int*   bcur    = boff + nb + 1;
    int*   row_ptr = bcur + nb;
    float* dinv    = (float*)(row_ptr + N + 1);
    short* Wb      = (short*)(dinv + N);

    int gT  = (E + ETILE - 1) / ETILE;   // 196 edge tiles
    int gM  = (N + 63) / 64;
    int gH1 = (N * 5 + TPB - 1) / TPB;
    int gH2 = (N + 47) / 48;             // 48 nodes per block (12/wave)

    k_wconv<<<(48 * 512) / TPB, TPB, 0, stream>>>(W, Wb, bcnt, nb);
    k_bhist<<<gT, TPB, 0, stream>>>(dst, bcnt, E, nb);
    k_boff<<<1, 512, 0, stream>>>(bcnt, boff, bcur, nb);
    k_part<<<gT, TPB, 0, stream>>>(src, dst, bcur, pairs, E, nb);
    k_sort<<<nb, TPB, 0, stream>>>(pairs, boff, csr, row_ptr, dinv, N, nb);

    k_matmul_mfma<<<gM, TPB, 0, stream>>>(x, Wb, dinv, z0b, N);

    k_hop1<<<gH1, TPB, 0, stream>>>(csr, row_ptr, dinv, z0b, z1b, N);
    k_hop2_lsm<<<gH2, TPB, 0, stream>>>(csr, row_ptr, dinv, z1b, b, out, N);
}